// Round 20
// baseline (35.222 us; speedup 1.0000x reference)
//
#include <hip/hip_runtime.h>

// QueryAndGroup: ball_query(r=0.2, nsample=32) + group xyz (centered) + group features.
// B=4, N=16384, M=2048, C=64. Output (B, 67, M, 32) f32.
//
// Ladder: R18 = 33.3us. This round, single variable: scan prefetch depth
// 1 -> 3 groups (software-pipelined register ring A/B/C). Theory: per 256-pt
// group, VALU ~160cy < L2 load latency ~450cy, so 1-deep exposes ~300cy/group;
// 3-deep covers ~320cy more. To fit the 64-VGPR occupancy cliff (alloc steps
// at 64), scan loads are SCALAR xyz (12 regs/group vs 16 for vf4; R10 showed
// scalar vs packed = neutral) and __launch_bounds__(128,8) forces the cap.
// Gather (4x4 float4 blocks, nt), prep (producer-XCD-aligned), swizzles: R18.

typedef float vf4 __attribute__((ext_vector_type(4)));

#define WPB 2
constexpr int Bc = 4, Nc = 16384, Mc = 2048, Cc = 64, Sc = 32;
constexpr int NQ = Bc * Mc;          // 8192 queries

// 1D grid of 1280 blocks: [0,1024) transpose, [1024,1280) xyz4 pack.
// Both roles: xcd = blockIdx%8, batch = xcd/2 (matches qg's consumer swizzle).
__global__ __launch_bounds__(256) void prep_kernel(
    const float* __restrict__ feat,  // (B, C, N)
    const float* __restrict__ xyz,   // (B, N, 3)
    float* __restrict__ featT,       // (B, N, C)
    vf4* __restrict__ xyz4)          // (B*N) packed {x,y,z,0}
{
    const int i   = blockIdx.x;
    const int xcd = i & 7;
    const int b   = xcd >> 1;

    if (i >= 1024) {
        const int j    = (i - 1024) >> 3;              // 0..31
        const int idxb = ((xcd & 1) << 5) + j;         // 0..63 within batch
        const int t    = idxb * 256 + threadIdx.x;     // 0..16383 within batch
        const float* p = xyz + ((size_t)b * Nc + t) * 3;
        vf4 v; v.x = p[0]; v.y = p[1]; v.z = p[2]; v.w = 0.0f;
        xyz4[(size_t)b * Nc + t] = v;
        return;
    }

    __shared__ float tile[64][65];
    const int nbase = ((((xcd & 1) << 7) + (i >> 3)) << 6);  // tile row base
    const int tn = threadIdx.x & 63;
    const int tq = threadIdx.x >> 6;  // 0..3
    const float* fb = feat + (size_t)b * Cc * Nc;
    float* ob = featT + (size_t)b * Nc * Cc;
    #pragma unroll
    for (int k = 0; k < 16; ++k) {
        const int c = k * 4 + tq;
        tile[tn][c] = fb[(size_t)c * Nc + nbase + tn];      // coalesced reads
    }
    __syncthreads();
    #pragma unroll
    for (int k = 0; k < 16; ++k) {
        const int nl = k * 4 + tq;
        ob[(size_t)(nbase + nl) * Cc + tn] = tile[nl][tn];  // coalesced writes
    }
}

__global__ __launch_bounds__(128, 8) void qg_kernel(
    const float* __restrict__ xyz,      // (B, N, 3) raw, for the scan
    const vf4* __restrict__ xyz4,       // (B*N) packed, for the gather
    const float* __restrict__ new_xyz,  // (B, M, 3)
    const float* __restrict__ featT,    // (B, N, C)
    float* __restrict__ out)            // (B, 67, M, 32)
{
#pragma clang fp contract(off)
    const int lane = threadIdx.x & 63;
    const int wv   = threadIdx.x >> 6;

    // Consumer XCD swizzle: batch b on XCDs {2b,2b+1}.
    const int xcd = blockIdx.x & 7;
    const int b   = xcd >> 1;
    const int m   = ((xcd & 1) << 10) + (blockIdx.x >> 3) * WPB + wv;

    __shared__ int sidx[WPB][Sc];

    const float r2 = 0.2f * 0.2f;
    const float* nz = new_xyz + (size_t)(b * Mc + m) * 3;
    const float qx = nz[0], qy = nz[1], qz = nz[2];
    const float* xb = xyz + (size_t)b * Nc * 3;

    int count = 0, firstIdx = 0;
    const unsigned long long lt = (1ull << lane) - 1ull;

    // ---- 3-deep software-pipelined scan (register ring A/B/C) ----
    float ax[4], ay[4], az[4], bx[4], by[4], bz[4];
    #pragma unroll
    for (int u = 0; u < 4; ++u) {
        const float* pp = xb + (size_t)(u * 64 + lane) * 3;
        ax[u] = pp[0]; ay[u] = pp[1]; az[u] = pp[2];
    }
    #pragma unroll
    for (int u = 0; u < 4; ++u) {
        const float* pp = xb + (size_t)(256 + u * 64 + lane) * 3;
        bx[u] = pp[0]; by[u] = pp[1]; bz[u] = pp[2];
    }
    for (int base = 0; base < Nc; base += 256) {
        // Issue group base+512 (clamped) -> C while A is processed.
        const int nb2 = (base + 512 < Nc) ? base + 512 : base;
        float cx[4], cy[4], cz[4];
        #pragma unroll
        for (int u = 0; u < 4; ++u) {
            const float* pp = xb + (size_t)(nb2 + u * 64 + lane) * 3;
            cx[u] = pp[0]; cy[u] = pp[1]; cz[u] = pp[2];
        }
        #pragma unroll
        for (int u = 0; u < 4; ++u) {
            const float dx = qx - ax[u], dy = qy - ay[u], dz = qz - az[u];
            float d2 = dx * dx + dy * dy;   // no fma: match np/jax f32 rounding
            d2 = d2 + dz * dz;
            const bool in = d2 < r2;
            const unsigned long long mask = __ballot(in);
            if (in) {
                const int slot = count + __popcll(mask & lt);
                if (slot < Sc) sidx[wv][slot] = base + u * 64 + lane;
            }
            if (count == 0 && mask != 0ull)
                firstIdx = base + u * 64 + __builtin_ctzll(mask);
            count += __popcll(mask);
        }
        if (count >= Sc) break;             // wave-uniform
        #pragma unroll
        for (int u = 0; u < 4; ++u) {       // rotate ring: A<-B, B<-C
            ax[u] = bx[u]; ay[u] = by[u]; az[u] = bz[u];
            bx[u] = cx[u]; by[u] = cy[u]; bz[u] = cz[u];
        }
    }
    {
        const int start = count < Sc ? count : Sc;
        if (start + lane < Sc) sidx[wv][start + lane] = firstIdx;
    }
    // Same-wave LDS visibility only; waves stay decoupled (no block barrier).
    asm volatile("s_waitcnt lgkmcnt(0)" ::: "memory");

    float* ob = out + ((size_t)b * 67 * Mc + m) * Sc;

    // ---- xyz channels 0..2 ----
    {
        const int s     = lane & 31;
        const int chalf = lane >> 5;
        const int myid  = sidx[wv][s];
        const vf4 p = xyz4[(size_t)b * Nc + myid];
        if (chalf == 0) {
            __builtin_nontemporal_store(p.x - qx, &ob[(size_t)0 * (Mc * Sc) + s]);
            __builtin_nontemporal_store(p.z - qz, &ob[(size_t)2 * (Mc * Sc) + s]);
        } else {
            __builtin_nontemporal_store(p.y - qy, &ob[(size_t)1 * (Mc * Sc) + s]);
        }
    }

    // ---- features: 4x4-block ownership, float4 loads AND stores ----
    const int cqlo = lane & 7;
    const int sq   = lane >> 3;
    int id4[4];
    #pragma unroll
    for (int k = 0; k < 4; ++k) id4[k] = sidx[wv][4 * sq + k];
    const float* fbase = featT + (size_t)b * Nc * Cc;

    #pragma unroll
    for (int i = 0; i < 2; ++i) {
        const int cq = cqlo + 8 * i;                 // 0..15
        vf4 v[4];
        #pragma unroll
        for (int k = 0; k < 4; ++k)                  // 4 rows, same channel-quad
            v[k] = *(const vf4*)(fbase + (size_t)id4[k] * Cc + 4 * cq);
        #pragma unroll
        for (int j = 0; j < 4; ++j) {                // in-register 4x4 transpose
            vf4 w;
            w.x = v[0][j]; w.y = v[1][j]; w.z = v[2][j]; w.w = v[3][j];
            __builtin_nontemporal_store(
                w, (vf4*)&ob[(size_t)(3 + 4 * cq + j) * (Mc * Sc) + 4 * sq]);
        }
    }
}

// Fallback if ws too small: fused kernel with direct (C,N) gather (same values).
__global__ __launch_bounds__(256) void qg_fallback_kernel(
    const float* __restrict__ xyz, const float* __restrict__ new_xyz,
    const float* __restrict__ feat, float* __restrict__ out)
{
#pragma clang fp contract(off)
    const int lane = threadIdx.x & 63;
    const int wv   = threadIdx.x >> 6;
    const int q    = blockIdx.x * 4 + wv;
    const int b    = q >> 11;
    const int m    = q & (Mc - 1);
    __shared__ int sidx[4][Sc];
    const float r2 = 0.2f * 0.2f;
    const float* nz = new_xyz + (size_t)(b * Mc + m) * 3;
    const float qx = nz[0], qy = nz[1], qz = nz[2];
    const float* xb = xyz + (size_t)b * Nc * 3;
    int count = 0, firstIdx = 0;
    const unsigned long long lt = (1ull << lane) - 1ull;
    for (int base = 0; base < Nc; base += 64) {
        const int i = base + lane;
        const float px = xb[i * 3], py = xb[i * 3 + 1], pz = xb[i * 3 + 2];
        const float dx = qx - px, dy = qy - py, dz = qz - pz;
        float d2 = dx * dx + dy * dy; d2 = d2 + dz * dz;
        const bool in = d2 < r2;
        const unsigned long long mask = __ballot(in);
        if (in) {
            const int slot = count + __popcll(mask & lt);
            if (slot < Sc) sidx[wv][slot] = i;
        }
        if (count == 0 && mask != 0ull) firstIdx = base + __builtin_ctzll(mask);
        count += __popcll(mask);
        if (count >= Sc) break;
    }
    const int start = count < Sc ? count : Sc;
    if (start + lane < Sc) sidx[wv][start + lane] = firstIdx;
    asm volatile("s_waitcnt lgkmcnt(0)" ::: "memory");
    const int s = lane & 31, chalf = lane >> 5;
    const int myid = sidx[wv][s];
    float* ob = out + ((size_t)b * 67 * Mc + m) * Sc;
    ob[(size_t)chalf * (Mc * Sc) + s] = xb[(size_t)myid * 3 + chalf] - (chalf ? qy : qx);
    if (chalf == 0)
        ob[(size_t)2 * (Mc * Sc) + s] = xb[(size_t)myid * 3 + 2] - qz;
    const float* fb = feat + (size_t)b * Cc * Nc;
    #pragma unroll
    for (int it = 0; it < 32; ++it) {
        const int c = it * 2 + chalf;
        ob[(size_t)(3 + c) * (Mc * Sc) + s] = fb[(size_t)c * Nc + myid];
    }
}

extern "C" void kernel_launch(void* const* d_in, const int* in_sizes, int n_in,
                              void* d_out, int out_size, void* d_ws, size_t ws_size,
                              hipStream_t stream) {
    const float* xyz     = (const float*)d_in[0];
    const float* new_xyz = (const float*)d_in[1];
    const float* feat    = (const float*)d_in[2];
    float* out           = (float*)d_out;

    const size_t featT_bytes = (size_t)Bc * Nc * Cc * sizeof(float);  // 16.8 MB
    const size_t xyz4_bytes  = (size_t)Bc * Nc * sizeof(vf4);         //  1.0 MB

    if (ws_size >= featT_bytes + xyz4_bytes) {
        float* featT = (float*)d_ws;
        vf4*   xyz4  = (vf4*)((char*)d_ws + featT_bytes);
        hipLaunchKernelGGL(prep_kernel, dim3(1280), dim3(256), 0, stream,
                           feat, xyz, featT, xyz4);
        hipLaunchKernelGGL(qg_kernel, dim3(NQ / WPB), dim3(128), 0, stream,
                           xyz, xyz4, new_xyz, featT, out);
    } else {
        hipLaunchKernelGGL(qg_fallback_kernel, dim3(NQ / 4), dim3(256), 0, stream,
                           xyz, new_xyz, feat, out);
    }
}

// Round 21
// 33.333 us; speedup vs baseline: 1.0567x; 1.0567x over previous
//
#include <hip/hip_runtime.h>

// QueryAndGroup: ball_query(r=0.2, nsample=32) + group xyz (centered) + group features.
// B=4, N=16384, M=2048, C=64. Output (B, 67, M, 32) f32.
//
// FINAL (= R18, best measured 33.3us): fused wave-per-query qg kernel with
//  - WPB=2 (128-thr blocks), consumer XCD swizzle (batch b -> XCDs {2b,2b+1})
//  - double-buffered 1-deep packed-vf4 scan (R19's 3-deep scalar pipeline
//    regressed: +VALU/addr overhead > latency coverage)
//  - featT row-gather with 4x4-block ownership: float4 loads AND float4 nt
//    stores (store-issue width was the last real lever, -1.2us)
//  - nt stores on all output (write-allocate displacement, -1us)
//  - prep kernel producer-XCD-aligned with the consumer swizzle (-0.2us)
// Falsified levers (11 probes): kernel splits (3x), device polling, work
// queues, coop-block scan, staged LDS scan, WPB=1, VMEM-count cut, 3-deep
// pipeline, nt-on-featT. Residual vs the 16.7us HBM floor: prep serialization
// (~5.5us) + distributed scan/gather latency; no remaining >=1us lever found.

typedef float vf4 __attribute__((ext_vector_type(4)));

#define WPB 2
constexpr int Bc = 4, Nc = 16384, Mc = 2048, Cc = 64, Sc = 32;
constexpr int NQ = Bc * Mc;          // 8192 queries

// 1D grid of 1280 blocks: [0,1024) transpose, [1024,1280) xyz4 pack.
// Both roles: xcd = blockIdx%8, batch = xcd/2 (matches qg's consumer swizzle).
__global__ __launch_bounds__(256) void prep_kernel(
    const float* __restrict__ feat,  // (B, C, N)
    const float* __restrict__ xyz,   // (B, N, 3)
    float* __restrict__ featT,       // (B, N, C)
    vf4* __restrict__ xyz4)          // (B*N) packed {x,y,z,0}
{
    const int i   = blockIdx.x;
    const int xcd = i & 7;
    const int b   = xcd >> 1;

    if (i >= 1024) {
        const int j    = (i - 1024) >> 3;              // 0..31
        const int idxb = ((xcd & 1) << 5) + j;         // 0..63 within batch
        const int t    = idxb * 256 + threadIdx.x;     // 0..16383 within batch
        const float* p = xyz + ((size_t)b * Nc + t) * 3;
        vf4 v; v.x = p[0]; v.y = p[1]; v.z = p[2]; v.w = 0.0f;
        xyz4[(size_t)b * Nc + t] = v;
        return;
    }

    __shared__ float tile[64][65];
    const int nbase = ((((xcd & 1) << 7) + (i >> 3)) << 6);  // tile row base
    const int tn = threadIdx.x & 63;
    const int tq = threadIdx.x >> 6;  // 0..3
    const float* fb = feat + (size_t)b * Cc * Nc;
    float* ob = featT + (size_t)b * Nc * Cc;
    #pragma unroll
    for (int k = 0; k < 16; ++k) {
        const int c = k * 4 + tq;
        tile[tn][c] = fb[(size_t)c * Nc + nbase + tn];      // coalesced reads
    }
    __syncthreads();
    #pragma unroll
    for (int k = 0; k < 16; ++k) {
        const int nl = k * 4 + tq;
        ob[(size_t)(nbase + nl) * Cc + tn] = tile[nl][tn];  // coalesced writes
    }
}

__global__ __launch_bounds__(128) void qg_kernel(
    const vf4* __restrict__ xyz4,       // (B*N) packed
    const float* __restrict__ new_xyz,  // (B, M, 3)
    const float* __restrict__ featT,    // (B, N, C)
    float* __restrict__ out)            // (B, 67, M, 32)
{
#pragma clang fp contract(off)
    const int lane = threadIdx.x & 63;
    const int wv   = threadIdx.x >> 6;

    // Consumer XCD swizzle: batch b on XCDs {2b,2b+1}.
    const int xcd = blockIdx.x & 7;
    const int b   = xcd >> 1;
    const int m   = ((xcd & 1) << 10) + (blockIdx.x >> 3) * WPB + wv;

    __shared__ int sidx[WPB][Sc];

    const float r2 = 0.2f * 0.2f;
    const float* nz = new_xyz + (size_t)(b * Mc + m) * 3;
    const float qx = nz[0], qy = nz[1], qz = nz[2];
    const vf4* xb4 = xyz4 + (size_t)b * Nc;

    int count = 0, firstIdx = 0;
    const unsigned long long lt = (1ull << lane) - 1ull;

    // Double-buffered scan.
    vf4 pv[4];
    #pragma unroll
    for (int u = 0; u < 4; ++u) pv[u] = xb4[u * 64 + lane];
    for (int base = 0; base < Nc; base += 256) {
        const int nb = (base + 256 < Nc) ? base + 256 : base;   // clamped prefetch
        vf4 nv[4];
        #pragma unroll
        for (int u = 0; u < 4; ++u) nv[u] = xb4[nb + u * 64 + lane];
        #pragma unroll
        for (int u = 0; u < 4; ++u) {
            const float dx = qx - pv[u].x, dy = qy - pv[u].y, dz = qz - pv[u].z;
            float d2 = dx * dx + dy * dy;   // no fma: match np/jax f32 rounding
            d2 = d2 + dz * dz;
            const bool in = d2 < r2;
            const unsigned long long mask = __ballot(in);
            if (in) {
                const int slot = count + __popcll(mask & lt);
                if (slot < Sc) sidx[wv][slot] = base + u * 64 + lane;
            }
            if (count == 0 && mask != 0ull)
                firstIdx = base + u * 64 + __builtin_ctzll(mask);
            count += __popcll(mask);
        }
        if (count >= Sc) break;             // wave-uniform
        #pragma unroll
        for (int u = 0; u < 4; ++u) pv[u] = nv[u];
    }
    {
        const int start = count < Sc ? count : Sc;
        if (start + lane < Sc) sidx[wv][start + lane] = firstIdx;
    }
    // Same-wave LDS visibility only; waves stay decoupled (no block barrier).
    asm volatile("s_waitcnt lgkmcnt(0)" ::: "memory");

    float* ob = out + ((size_t)b * 67 * Mc + m) * Sc;

    // ---- xyz channels 0..2 ----
    {
        const int s     = lane & 31;
        const int chalf = lane >> 5;
        const int myid  = sidx[wv][s];
        const vf4 p = xb4[myid];
        if (chalf == 0) {
            __builtin_nontemporal_store(p.x - qx, &ob[(size_t)0 * (Mc * Sc) + s]);
            __builtin_nontemporal_store(p.z - qz, &ob[(size_t)2 * (Mc * Sc) + s]);
        } else {
            __builtin_nontemporal_store(p.y - qy, &ob[(size_t)1 * (Mc * Sc) + s]);
        }
    }

    // ---- features: 4x4-block ownership, float4 loads AND stores ----
    const int cqlo = lane & 7;
    const int sq   = lane >> 3;
    int id4[4];
    #pragma unroll
    for (int k = 0; k < 4; ++k) id4[k] = sidx[wv][4 * sq + k];
    const float* fbase = featT + (size_t)b * Nc * Cc;

    #pragma unroll
    for (int i = 0; i < 2; ++i) {
        const int cq = cqlo + 8 * i;                 // 0..15
        vf4 v[4];
        #pragma unroll
        for (int k = 0; k < 4; ++k)                  // 4 rows, same channel-quad
            v[k] = *(const vf4*)(fbase + (size_t)id4[k] * Cc + 4 * cq);
        #pragma unroll
        for (int j = 0; j < 4; ++j) {                // in-register 4x4 transpose
            vf4 w;
            w.x = v[0][j]; w.y = v[1][j]; w.z = v[2][j]; w.w = v[3][j];
            __builtin_nontemporal_store(
                w, (vf4*)&ob[(size_t)(3 + 4 * cq + j) * (Mc * Sc) + 4 * sq]);
        }
    }
}

// Fallback if ws too small: fused kernel with direct (C,N) gather (same values).
__global__ __launch_bounds__(256) void qg_fallback_kernel(
    const float* __restrict__ xyz, const float* __restrict__ new_xyz,
    const float* __restrict__ feat, float* __restrict__ out)
{
#pragma clang fp contract(off)
    const int lane = threadIdx.x & 63;
    const int wv   = threadIdx.x >> 6;
    const int q    = blockIdx.x * 4 + wv;
    const int b    = q >> 11;
    const int m    = q & (Mc - 1);
    __shared__ int sidx[4][Sc];
    const float r2 = 0.2f * 0.2f;
    const float* nz = new_xyz + (size_t)(b * Mc + m) * 3;
    const float qx = nz[0], qy = nz[1], qz = nz[2];
    const float* xb = xyz + (size_t)b * Nc * 3;
    int count = 0, firstIdx = 0;
    const unsigned long long lt = (1ull << lane) - 1ull;
    for (int base = 0; base < Nc; base += 64) {
        const int i = base + lane;
        const float px = xb[i * 3], py = xb[i * 3 + 1], pz = xb[i * 3 + 2];
        const float dx = qx - px, dy = qy - py, dz = qz - pz;
        float d2 = dx * dx + dy * dy; d2 = d2 + dz * dz;
        const bool in = d2 < r2;
        const unsigned long long mask = __ballot(in);
        if (in) {
            const int slot = count + __popcll(mask & lt);
            if (slot < Sc) sidx[wv][slot] = i;
        }
        if (count == 0 && mask != 0ull) firstIdx = base + __builtin_ctzll(mask);
        count += __popcll(mask);
        if (count >= Sc) break;
    }
    const int start = count < Sc ? count : Sc;
    if (start + lane < Sc) sidx[wv][start + lane] = firstIdx;
    asm volatile("s_waitcnt lgkmcnt(0)" ::: "memory");
    const int s = lane & 31, chalf = lane >> 5;
    const int myid = sidx[wv][s];
    float* ob = out + ((size_t)b * 67 * Mc + m) * Sc;
    ob[(size_t)chalf * (Mc * Sc) + s] = xb[(size_t)myid * 3 + chalf] - (chalf ? qy : qx);
    if (chalf == 0)
        ob[(size_t)2 * (Mc * Sc) + s] = xb[(size_t)myid * 3 + 2] - qz;
    const float* fb = feat + (size_t)b * Cc * Nc;
    #pragma unroll
    for (int it = 0; it < 32; ++it) {
        const int c = it * 2 + chalf;
        ob[(size_t)(3 + c) * (Mc * Sc) + s] = fb[(size_t)c * Nc + myid];
    }
}

extern "C" void kernel_launch(void* const* d_in, const int* in_sizes, int n_in,
                              void* d_out, int out_size, void* d_ws, size_t ws_size,
                              hipStream_t stream) {
    const float* xyz     = (const float*)d_in[0];
    const float* new_xyz = (const float*)d_in[1];
    const float* feat    = (const float*)d_in[2];
    float* out           = (float*)d_out;

    const size_t featT_bytes = (size_t)Bc * Nc * Cc * sizeof(float);  // 16.8 MB
    const size_t xyz4_bytes  = (size_t)Bc * Nc * sizeof(vf4);         //  1.0 MB

    if (ws_size >= featT_bytes + xyz4_bytes) {
        float* featT = (float*)d_ws;
        vf4*   xyz4  = (vf4*)((char*)d_ws + featT_bytes);
        hipLaunchKernelGGL(prep_kernel, dim3(1280), dim3(256), 0, stream,
                           feat, xyz, featT, xyz4);
        hipLaunchKernelGGL(qg_kernel, dim3(NQ / WPB), dim3(128), 0, stream,
                           xyz4, new_xyz, featT, out);
    } else {
        hipLaunchKernelGGL(qg_fallback_kernel, dim3(NQ / 4), dim3(256), 0, stream,
                           xyz, new_xyz, feat, out);
    }
}